// Round 1
// baseline (2259.302 us; speedup 1.0000x reference)
//
#include <hip/hip_runtime.h>
#include <hip/hip_bf16.h>

#define N_NODES 50000
#define N_EDGES 600000
#define N_GRAPHS 1000
#define IN_DIM 100
#define HID 128
#define OUT_DIM 128

#define BM 64
#define BN 128
#define BKK 32

// ---------------- degree ----------------
__global__ __launch_bounds__(256) void deg_kernel(const int* __restrict__ dst, float* __restrict__ deg) {
    int e = blockIdx.x * 256 + threadIdx.x;
    if (e < N_EDGES) atomicAdd(&deg[dst[e]], 1.0f);
}

__global__ __launch_bounds__(256) void dinv_kernel(float* __restrict__ dinv) {
    int i = blockIdx.x * 256 + threadIdx.x;
    if (i < N_NODES) {
        float d = dinv[i];            // currently holds deg (edge count)
        dinv[i] = 1.0f / sqrtf(d + 1.0f);
    }
}

// ---------------- fused GEMM: h = A@W ; agg = h*dinv^2 + bias ----------------
__global__ __launch_bounds__(256) void gemm_fused(
    const float* __restrict__ A, const float* __restrict__ W,
    const float* __restrict__ bias, const float* __restrict__ dinv,
    float* __restrict__ h, float* __restrict__ agg, int M, int K)
{
    __shared__ float As[BKK][BM + 4];
    __shared__ float Ws[BKK][BN];
    const int tid = threadIdx.x;
    const int row0 = blockIdx.x * BM;
    const int tx = tid & 31;   // col group: cols tx*4..tx*4+3
    const int ty = tid >> 5;   // row group: rows ty*8..ty*8+7

    float acc[8][4];
#pragma unroll
    for (int i = 0; i < 8; i++)
#pragma unroll
        for (int j = 0; j < 4; j++) acc[i][j] = 0.0f;

    for (int k0 = 0; k0 < K; k0 += BKK) {
        // stage W tile: 32x128 = 1024 float4, 4 per thread
#pragma unroll
        for (int it = 0; it < 4; ++it) {
            int lin = tid + it * 256;          // float4 slot
            int kl  = lin >> 5;                // 32 float4 per row
            int c4  = lin & 31;
            int kg  = k0 + kl;
            float4 v = make_float4(0.f, 0.f, 0.f, 0.f);
            if (kg < K) v = *reinterpret_cast<const float4*>(W + (size_t)kg * BN + c4 * 4);
            *reinterpret_cast<float4*>(&Ws[kl][c4 * 4]) = v;
        }
        // stage A tile transposed: 64 rows x 32 k = 512 float4, 2 per thread
#pragma unroll
        for (int it = 0; it < 2; ++it) {
            int lin = tid + it * 256;          // 0..511
            int r   = lin >> 3;                // 8 float4 per row
            int kq  = lin & 7;
            int grow = row0 + r;
            int kg   = k0 + kq * 4;
            float4 v = make_float4(0.f, 0.f, 0.f, 0.f);
            if (grow < M) {
                if (kg + 3 < K) {
                    v = *reinterpret_cast<const float4*>(A + (size_t)grow * K + kg);
                } else {
                    float t0 = (kg + 0 < K) ? A[(size_t)grow * K + kg + 0] : 0.f;
                    float t1 = (kg + 1 < K) ? A[(size_t)grow * K + kg + 1] : 0.f;
                    float t2 = (kg + 2 < K) ? A[(size_t)grow * K + kg + 2] : 0.f;
                    float t3 = (kg + 3 < K) ? A[(size_t)grow * K + kg + 3] : 0.f;
                    v = make_float4(t0, t1, t2, t3);
                }
            }
            As[kq * 4 + 0][r] = v.x;
            As[kq * 4 + 1][r] = v.y;
            As[kq * 4 + 2][r] = v.z;
            As[kq * 4 + 3][r] = v.w;
        }
        __syncthreads();
#pragma unroll
        for (int k = 0; k < BKK; k++) {
            float a[8];
#pragma unroll
            for (int i = 0; i < 8; i++) a[i] = As[k][ty * 8 + i];
            float4 bv = *reinterpret_cast<const float4*>(&Ws[k][tx * 4]);
#pragma unroll
            for (int i = 0; i < 8; i++) {
                acc[i][0] += a[i] * bv.x;
                acc[i][1] += a[i] * bv.y;
                acc[i][2] += a[i] * bv.z;
                acc[i][3] += a[i] * bv.w;
            }
        }
        __syncthreads();
    }

    float4 bb = *reinterpret_cast<const float4*>(bias + tx * 4);
#pragma unroll
    for (int i = 0; i < 8; i++) {
        int grow = row0 + ty * 8 + i;
        if (grow >= M) continue;
        float dv = dinv[grow];
        float d2 = dv * dv;
        float4 hv = make_float4(acc[i][0], acc[i][1], acc[i][2], acc[i][3]);
        *reinterpret_cast<float4*>(h + (size_t)grow * BN + tx * 4) = hv;
        float4 av = make_float4(hv.x * d2 + bb.x, hv.y * d2 + bb.y,
                                hv.z * d2 + bb.z, hv.w * d2 + bb.w);
        *reinterpret_cast<float4*>(agg + (size_t)grow * BN + tx * 4) = av;
    }
}

// ---------------- edge scatter: agg[dst] += h[src]*dinv[src]*dinv[dst] ----------------
__global__ __launch_bounds__(256) void scatter_edges(
    const float* __restrict__ h, const float* __restrict__ dinv,
    const int* __restrict__ src, const int* __restrict__ dst,
    float* __restrict__ agg)
{
    int gid = blockIdx.x * 256 + threadIdx.x;
    int e = gid >> 5;
    if (e >= N_EDGES) return;
    int lane = gid & 31;
    int s = src[e], d = dst[e];
    float nrm = dinv[s] * dinv[d];
    float4 v = *reinterpret_cast<const float4*>(h + (size_t)s * HID + lane * 4);
    float* ap = agg + (size_t)d * HID + lane * 4;
    atomicAdd(ap + 0, v.x * nrm);
    atomicAdd(ap + 1, v.y * nrm);
    atomicAdd(ap + 2, v.z * nrm);
    atomicAdd(ap + 3, v.w * nrm);
}

// ---------------- relu: out[i] = max(agg[i], 0) ----------------
__global__ __launch_bounds__(256) void relu_kernel(const float* __restrict__ in, float* __restrict__ out) {
    int i = blockIdx.x * 256 + threadIdx.x;
    const int n4 = (N_NODES * HID) / 4;
    if (i < n4) {
        float4 v = reinterpret_cast<const float4*>(in)[i];
        v.x = fmaxf(v.x, 0.f); v.y = fmaxf(v.y, 0.f);
        v.z = fmaxf(v.z, 0.f); v.w = fmaxf(v.w, 0.f);
        reinterpret_cast<float4*>(out)[i] = v;
    }
}

// ---------------- pool: sums[batch[i]] += relu(agg2[i]); cnt[batch[i]] += 1 ----------------
__global__ __launch_bounds__(256) void pool_kernel(
    const float* __restrict__ agg2, const int* __restrict__ batch,
    float* __restrict__ sums, float* __restrict__ cnt)
{
    int gid = blockIdx.x * 256 + threadIdx.x;
    int node = gid >> 5;
    if (node >= N_NODES) return;
    int lane = gid & 31;
    int b = batch[node];
    float4 v = *reinterpret_cast<const float4*>(agg2 + (size_t)node * HID + lane * 4);
    v.x = fmaxf(v.x, 0.f); v.y = fmaxf(v.y, 0.f);
    v.z = fmaxf(v.z, 0.f); v.w = fmaxf(v.w, 0.f);
    float* sp = sums + (size_t)b * HID + lane * 4;
    atomicAdd(sp + 0, v.x);
    atomicAdd(sp + 1, v.y);
    atomicAdd(sp + 2, v.z);
    atomicAdd(sp + 3, v.w);
    if (lane == 0) atomicAdd(&cnt[b], 1.0f);
}

// ---------------- head: out[g] = (sums[g]/max(cnt,1)) @ Wp + bp ----------------
__global__ __launch_bounds__(128) void final_gemm(
    const float* __restrict__ sums, const float* __restrict__ cnt,
    const float* __restrict__ Wp, const float* __restrict__ bp,
    float* __restrict__ out)
{
    __shared__ float p[128];
    int g = blockIdx.x;
    int j = threadIdx.x;
    float inv = 1.0f / fmaxf(cnt[g], 1.0f);
    p[j] = sums[(size_t)g * HID + j] * inv;
    __syncthreads();
    float acc = bp[j];
#pragma unroll 8
    for (int k = 0; k < HID; k++) acc += p[k] * Wp[(size_t)k * OUT_DIM + j];
    out[(size_t)g * OUT_DIM + j] = acc;
}

extern "C" void kernel_launch(void* const* d_in, const int* in_sizes, int n_in,
                              void* d_out, int out_size, void* d_ws, size_t ws_size,
                              hipStream_t stream) {
    const float* x   = (const float*)d_in[0];
    const int*   ei  = (const int*)d_in[1];
    const int*   src = ei;
    const int*   dst = ei + N_EDGES;
    const int*   batch = (const int*)d_in[2];
    const float* W1 = (const float*)d_in[3];
    const float* b1 = (const float*)d_in[4];
    const float* W2 = (const float*)d_in[5];
    const float* b2 = (const float*)d_in[6];
    const float* Wp = (const float*)d_in[7];
    const float* bp = (const float*)d_in[8];
    float* out = (float*)d_out;

    // workspace layout (floats)
    float* ws   = (float*)d_ws;
    float* dinv = ws;                       // 50048
    float* h    = ws + 50048;               // 6,400,000
    float* agg  = h + 6400000;              // 6,400,000
    float* sums = agg + 6400000;            // 128,000
    float* cnt  = sums + 128000;            // 1,000

    // zero deg and pool accumulators
    hipMemsetAsync(dinv, 0, N_NODES * sizeof(float), stream);
    hipMemsetAsync(sums, 0, (N_GRAPHS * HID + N_GRAPHS) * sizeof(float), stream);

    // degree + dinv
    deg_kernel<<<(N_EDGES + 255) / 256, 256, 0, stream>>>(dst, dinv);
    dinv_kernel<<<(N_NODES + 255) / 256, 256, 0, stream>>>(dinv);

    const int gemm_blocks = (N_NODES + BM - 1) / BM;
    const int scatter_blocks = (N_EDGES * 32 + 255) / 256;

    // layer 1
    gemm_fused<<<gemm_blocks, 256, 0, stream>>>(x, W1, b1, dinv, h, agg, N_NODES, IN_DIM);
    scatter_edges<<<scatter_blocks, 256, 0, stream>>>(h, dinv, src, dst, agg);
    relu_kernel<<<(N_NODES * HID / 4 + 255) / 256, 256, 0, stream>>>(agg, h);

    // layer 2 (h now holds relu(layer1)); in-place h -> h2, agg -> agg2
    gemm_fused<<<gemm_blocks, 256, 0, stream>>>(h, W2, b2, dinv, h, agg, N_NODES, HID);
    scatter_edges<<<scatter_blocks, 256, 0, stream>>>(h, dinv, src, dst, agg);

    // pool (fused relu) + head
    pool_kernel<<<(N_NODES * 32 + 255) / 256, 256, 0, stream>>>(agg, batch, sums, cnt);
    final_gemm<<<N_GRAPHS, 128, 0, stream>>>(sums, cnt, Wp, bp, out);
}

// Round 2
// 339.685 us; speedup vs baseline: 6.6512x; 6.6512x over previous
//
#include <hip/hip_runtime.h>
#include <hip/hip_bf16.h>

#define N_NODES 50000
#define N_EDGES 600000
#define N_GRAPHS 1000
#define IN_DIM 100
#define HID 128
#define OUT_DIM 128

#define BM 64
#define BN 128
#define BKK 32

// ---------------- degree (int) ----------------
__global__ __launch_bounds__(256) void deg_count(const int* __restrict__ dst, int* __restrict__ deg) {
    int e = blockIdx.x * 256 + threadIdx.x;
    if (e < N_EDGES) atomicAdd(&deg[dst[e]], 1);
}

__global__ __launch_bounds__(256) void dinv_from_deg(const int* __restrict__ deg, float* __restrict__ dinv) {
    int i = blockIdx.x * 256 + threadIdx.x;
    if (i < N_NODES) dinv[i] = rsqrtf((float)deg[i] + 1.0f);
}

// ---------------- exclusive scan over 50000 degrees (single block) ----------------
#define SCAN_T 1024
#define SCAN_E 49   // ceil(50000/1024)
__global__ __launch_bounds__(SCAN_T) void scan_deg(const int* __restrict__ deg, int* __restrict__ off) {
    __shared__ int part[SCAN_T];
    int t = threadIdx.x;
    int base = t * SCAN_E;
    int s = 0;
#pragma unroll
    for (int i = 0; i < SCAN_E; i++) {
        int idx = base + i;
        if (idx < N_NODES) s += deg[idx];
    }
    part[t] = s;
    __syncthreads();
    // Hillis-Steele inclusive scan
    for (int d = 1; d < SCAN_T; d <<= 1) {
        int v = (t >= d) ? part[t - d] : 0;
        __syncthreads();
        part[t] += v;
        __syncthreads();
    }
    int run = (t == 0) ? 0 : part[t - 1];
#pragma unroll
    for (int i = 0; i < SCAN_E; i++) {
        int idx = base + i;
        if (idx < N_NODES) { off[idx] = run; run += deg[idx]; }
    }
    if (t == SCAN_T - 1) off[N_NODES] = run;
}

// ---------------- fill CSR: csr_src grouped by dst ----------------
__global__ __launch_bounds__(256) void fill_csr(
    const int* __restrict__ src, const int* __restrict__ dst,
    const int* __restrict__ off, int* __restrict__ cursor, int* __restrict__ csr_src)
{
    int e = blockIdx.x * 256 + threadIdx.x;
    if (e >= N_EDGES) return;
    int d = dst[e];
    int pos = off[d] + atomicAdd(&cursor[d], 1);
    csr_src[pos] = src[e];
}

// ---------------- graph segment boundaries from sorted batch ----------------
__global__ __launch_bounds__(256) void graph_bounds(const int* __restrict__ batch, int* __restrict__ starts) {
    int i = blockIdx.x * 256 + threadIdx.x;
    if (i >= N_NODES) return;
    int b = batch[i];
    if (i == 0) {
        for (int g = 0; g <= b; ++g) starts[g] = 0;
    } else {
        int pb = batch[i - 1];
        for (int g = pb + 1; g <= b; ++g) starts[g] = i;
    }
    if (i == N_NODES - 1) {
        for (int g = b + 1; g <= N_GRAPHS; ++g) starts[g] = N_NODES;
    }
}

// ---------------- GEMM: h = A@W (f32, LDS-tiled) ----------------
__global__ __launch_bounds__(256) void gemm_h(
    const float* __restrict__ A, const float* __restrict__ W,
    float* __restrict__ h, int M, int K)
{
    __shared__ float As[BKK][BM + 4];
    __shared__ float Ws[BKK][BN];
    const int tid = threadIdx.x;
    const int row0 = blockIdx.x * BM;
    const int tx = tid & 31;   // col group: cols tx*4..tx*4+3
    const int ty = tid >> 5;   // row group: rows ty*8..ty*8+7

    float acc[8][4];
#pragma unroll
    for (int i = 0; i < 8; i++)
#pragma unroll
        for (int j = 0; j < 4; j++) acc[i][j] = 0.0f;

    for (int k0 = 0; k0 < K; k0 += BKK) {
#pragma unroll
        for (int it = 0; it < 4; ++it) {
            int lin = tid + it * 256;
            int kl  = lin >> 5;
            int c4  = lin & 31;
            int kg  = k0 + kl;
            float4 v = make_float4(0.f, 0.f, 0.f, 0.f);
            if (kg < K) v = *reinterpret_cast<const float4*>(W + (size_t)kg * BN + c4 * 4);
            *reinterpret_cast<float4*>(&Ws[kl][c4 * 4]) = v;
        }
#pragma unroll
        for (int it = 0; it < 2; ++it) {
            int lin = tid + it * 256;
            int r   = lin >> 3;
            int kq  = lin & 7;
            int grow = row0 + r;
            int kg   = k0 + kq * 4;
            float4 v = make_float4(0.f, 0.f, 0.f, 0.f);
            if (grow < M) {
                if (kg + 3 < K) {
                    v = *reinterpret_cast<const float4*>(A + (size_t)grow * K + kg);
                } else {
                    float t0 = (kg + 0 < K) ? A[(size_t)grow * K + kg + 0] : 0.f;
                    float t1 = (kg + 1 < K) ? A[(size_t)grow * K + kg + 1] : 0.f;
                    float t2 = (kg + 2 < K) ? A[(size_t)grow * K + kg + 2] : 0.f;
                    float t3 = (kg + 3 < K) ? A[(size_t)grow * K + kg + 3] : 0.f;
                    v = make_float4(t0, t1, t2, t3);
                }
            }
            As[kq * 4 + 0][r] = v.x;
            As[kq * 4 + 1][r] = v.y;
            As[kq * 4 + 2][r] = v.z;
            As[kq * 4 + 3][r] = v.w;
        }
        __syncthreads();
#pragma unroll
        for (int k = 0; k < BKK; k++) {
            float a[8];
#pragma unroll
            for (int i = 0; i < 8; i++) a[i] = As[k][ty * 8 + i];
            float4 bv = *reinterpret_cast<const float4*>(&Ws[k][tx * 4]);
#pragma unroll
            for (int i = 0; i < 8; i++) {
                acc[i][0] += a[i] * bv.x;
                acc[i][1] += a[i] * bv.y;
                acc[i][2] += a[i] * bv.z;
                acc[i][3] += a[i] * bv.w;
            }
        }
        __syncthreads();
    }

#pragma unroll
    for (int i = 0; i < 8; i++) {
        int grow = row0 + ty * 8 + i;
        if (grow >= M) continue;
        float4 hv = make_float4(acc[i][0], acc[i][1], acc[i][2], acc[i][3]);
        *reinterpret_cast<float4*>(h + (size_t)grow * BN + tx * 4) = hv;
    }
}

// ---------------- gather: out[d] = relu( sum_{e:dst=d} h[src]*dinv[s]*dinv[d]
//                                        + h[d]*dinv[d]^2 + bias ) ----------------
__global__ __launch_bounds__(256) void gather_agg(
    const float* __restrict__ h, const float* __restrict__ dinv,
    const int* __restrict__ off, const int* __restrict__ csr_src,
    const float* __restrict__ bias, float* __restrict__ out)
{
    int gid = blockIdx.x * 256 + threadIdx.x;
    int node = gid >> 5;
    if (node >= N_NODES) return;
    int lane = gid & 31;

    int beg = off[node], end = off[node + 1];
    float dd = dinv[node];

    float4 hv = *reinterpret_cast<const float4*>(h + (size_t)node * HID + lane * 4);
    float4 bb = *reinterpret_cast<const float4*>(bias + lane * 4);
    float d2 = dd * dd;
    float4 acc = make_float4(hv.x * d2 + bb.x, hv.y * d2 + bb.y,
                             hv.z * d2 + bb.z, hv.w * d2 + bb.w);

    int s_next = (beg < end) ? csr_src[beg] : 0;
    for (int j = beg; j < end; ++j) {
        int s = s_next;
        if (j + 1 < end) s_next = csr_src[j + 1];
        float nrm = dinv[s] * dd;
        float4 v = *reinterpret_cast<const float4*>(h + (size_t)s * HID + lane * 4);
        acc.x += v.x * nrm;
        acc.y += v.y * nrm;
        acc.z += v.z * nrm;
        acc.w += v.w * nrm;
    }
    acc.x = fmaxf(acc.x, 0.f); acc.y = fmaxf(acc.y, 0.f);
    acc.z = fmaxf(acc.z, 0.f); acc.w = fmaxf(acc.w, 0.f);
    *reinterpret_cast<float4*>(out + (size_t)node * HID + lane * 4) = acc;
}

// ---------------- fused mean-pool + head: out[g] = (mean x[g-range]) @ Wp + bp ----------------
__global__ __launch_bounds__(128) void pool_head(
    const float* __restrict__ xbuf, const int* __restrict__ starts,
    const float* __restrict__ Wp, const float* __restrict__ bp,
    float* __restrict__ out)
{
    __shared__ float p[128];
    int g = blockIdx.x;
    int t = threadIdx.x;
    int s0 = starts[g], s1 = starts[g + 1];
    float acc = 0.f;
    for (int n = s0; n < s1; ++n) acc += xbuf[(size_t)n * HID + t];
    float cntf = (float)(s1 - s0);
    p[t] = acc / fmaxf(cntf, 1.0f);
    __syncthreads();
    float o = bp[t];
#pragma unroll 8
    for (int k = 0; k < HID; k++) o += p[k] * Wp[(size_t)k * OUT_DIM + t];
    out[(size_t)g * OUT_DIM + t] = o;
}

extern "C" void kernel_launch(void* const* d_in, const int* in_sizes, int n_in,
                              void* d_out, int out_size, void* d_ws, size_t ws_size,
                              hipStream_t stream) {
    const float* x   = (const float*)d_in[0];
    const int*   ei  = (const int*)d_in[1];
    const int*   src = ei;
    const int*   dst = ei + N_EDGES;
    const int*   batch = (const int*)d_in[2];
    const float* W1 = (const float*)d_in[3];
    const float* b1 = (const float*)d_in[4];
    const float* W2 = (const float*)d_in[5];
    const float* b2 = (const float*)d_in[6];
    const float* Wp = (const float*)d_in[7];
    const float* bp = (const float*)d_in[8];
    float* out = (float*)d_out;

    // ---- workspace layout ----
    float* ws    = (float*)d_ws;
    float* dinv  = ws;                          // 50,000 f
    float* hbuf  = ws + 50048;                  // 6,400,000 f
    float* xbuf  = hbuf + 6400000;              // 6,400,000 f
    int*   off     = (int*)(xbuf + 6400000);    // 50,001 i
    int*   csr_src = off + 50056;               // 600,000 i
    int*   starts  = csr_src + 600000;          // 1,001 i
    // aliases (live only before the big buffers are first written):
    int*   deg_i  = (int*)hbuf;                 // used before gemm1 writes hbuf
    int*   cursor = (int*)xbuf;                 // used before gather1 writes xbuf

    // ---- CSR build ----
    hipMemsetAsync(deg_i, 0, N_NODES * sizeof(int), stream);
    deg_count<<<(N_EDGES + 255) / 256, 256, 0, stream>>>(dst, deg_i);
    dinv_from_deg<<<(N_NODES + 255) / 256, 256, 0, stream>>>(deg_i, dinv);
    scan_deg<<<1, SCAN_T, 0, stream>>>(deg_i, off);
    hipMemsetAsync(cursor, 0, N_NODES * sizeof(int), stream);
    fill_csr<<<(N_EDGES + 255) / 256, 256, 0, stream>>>(src, dst, off, cursor, csr_src);
    graph_bounds<<<(N_NODES + 255) / 256, 256, 0, stream>>>(batch, starts);

    const int gemm_blocks = (N_NODES + BM - 1) / BM;
    const int gather_blocks = (N_NODES * 32 + 255) / 256;

    // ---- layer 1 ----
    gemm_h<<<gemm_blocks, 256, 0, stream>>>(x, W1, hbuf, N_NODES, IN_DIM);
    gather_agg<<<gather_blocks, 256, 0, stream>>>(hbuf, dinv, off, csr_src, b1, xbuf);

    // ---- layer 2 ----
    gemm_h<<<gemm_blocks, 256, 0, stream>>>(xbuf, W2, hbuf, N_NODES, HID);
    gather_agg<<<gather_blocks, 256, 0, stream>>>(hbuf, dinv, off, csr_src, b2, xbuf);

    // ---- pool + head ----
    pool_head<<<N_GRAPHS, 128, 0, stream>>>(xbuf, starts, Wp, bp, out);
}

// Round 3
// 271.865 us; speedup vs baseline: 8.3104x; 1.2495x over previous
//
#include <hip/hip_runtime.h>
#include <hip/hip_bf16.h>

#define N_NODES 50000
#define N_EDGES 600000
#define N_GRAPHS 1000
#define IN_DIM 100
#define HID 128
#define OUT_DIM 128

#define BM 64
#define BN 128
#define BKK 32

// ---------------- degree (int) ----------------
__global__ __launch_bounds__(256) void deg_count(const int* __restrict__ dst, int* __restrict__ deg) {
    int e = blockIdx.x * 256 + threadIdx.x;
    if (e < N_EDGES) atomicAdd(&deg[dst[e]], 1);
}

__global__ __launch_bounds__(256) void dinv_from_deg(const int* __restrict__ deg, float* __restrict__ dinv) {
    int i = blockIdx.x * 256 + threadIdx.x;
    if (i < N_NODES) dinv[i] = rsqrtf((float)deg[i] + 1.0f);
}

// ---------------- range allocator: off[i] = disjoint base for node i's edges ----
// Order across blocks is arbitrary (atomic) but ranges are disjoint & contiguous,
// which is all the gather needs. end = off[i] + deg[i].
__global__ __launch_bounds__(256) void alloc_off(const int* __restrict__ deg,
                                                 int* __restrict__ off,
                                                 int* __restrict__ total) {
    int i = blockIdx.x * 256 + threadIdx.x;
    int v = (i < N_NODES) ? deg[i] : 0;
    int lane = threadIdx.x & 63;
    int wid  = threadIdx.x >> 6;
    // wave inclusive scan
    int x = v;
#pragma unroll
    for (int d = 1; d < 64; d <<= 1) {
        int y = __shfl_up(x, d, 64);
        if (lane >= d) x += y;
    }
    __shared__ int wsum[4];
    __shared__ int wbase[4];
    if (lane == 63) wsum[wid] = x;
    __syncthreads();
    if (threadIdx.x == 0) {
        int s0 = wsum[0], s1 = wsum[1], s2 = wsum[2], s3 = wsum[3];
        int base = atomicAdd(total, s0 + s1 + s2 + s3);
        wbase[0] = base;
        wbase[1] = base + s0;
        wbase[2] = base + s0 + s1;
        wbase[3] = base + s0 + s1 + s2;
    }
    __syncthreads();
    if (i < N_NODES) off[i] = wbase[wid] + x - v;   // exclusive within block
}

// ---------------- fill CSR: csr_src grouped by dst ----------------
__global__ __launch_bounds__(256) void fill_csr(
    const int* __restrict__ src, const int* __restrict__ dst,
    const int* __restrict__ off, int* __restrict__ cursor, int* __restrict__ csr_src)
{
    int e = blockIdx.x * 256 + threadIdx.x;
    if (e >= N_EDGES) return;
    int d = dst[e];
    int pos = off[d] + atomicAdd(&cursor[d], 1);
    csr_src[pos] = src[e];
}

// ---------------- graph segment boundaries from sorted batch ----------------
__global__ __launch_bounds__(256) void graph_bounds(const int* __restrict__ batch, int* __restrict__ starts) {
    int i = blockIdx.x * 256 + threadIdx.x;
    if (i >= N_NODES) return;
    int b = batch[i];
    if (i == 0) {
        for (int g = 0; g <= b; ++g) starts[g] = 0;
    } else {
        int pb = batch[i - 1];
        for (int g = pb + 1; g <= b; ++g) starts[g] = i;
    }
    if (i == N_NODES - 1) {
        for (int g = b + 1; g <= N_GRAPHS; ++g) starts[g] = N_NODES;
    }
}

// ---------------- GEMM: h' = (A@W) * dinv[row]  (f32, LDS-tiled) ----------------
__global__ __launch_bounds__(256) void gemm_hs(
    const float* __restrict__ A, const float* __restrict__ W,
    const float* __restrict__ dinv, float* __restrict__ h, int M, int K)
{
    __shared__ float As[BKK][BM + 4];
    __shared__ float Ws[BKK][BN];
    const int tid = threadIdx.x;
    const int row0 = blockIdx.x * BM;
    const int tx = tid & 31;   // col group: cols tx*4..tx*4+3
    const int ty = tid >> 5;   // row group: rows ty*8..ty*8+7

    float acc[8][4];
#pragma unroll
    for (int i = 0; i < 8; i++)
#pragma unroll
        for (int j = 0; j < 4; j++) acc[i][j] = 0.0f;

    for (int k0 = 0; k0 < K; k0 += BKK) {
#pragma unroll
        for (int it = 0; it < 4; ++it) {
            int lin = tid + it * 256;
            int kl  = lin >> 5;
            int c4  = lin & 31;
            int kg  = k0 + kl;
            float4 v = make_float4(0.f, 0.f, 0.f, 0.f);
            if (kg < K) v = *reinterpret_cast<const float4*>(W + (size_t)kg * BN + c4 * 4);
            *reinterpret_cast<float4*>(&Ws[kl][c4 * 4]) = v;
        }
#pragma unroll
        for (int it = 0; it < 2; ++it) {
            int lin = tid + it * 256;
            int r   = lin >> 3;
            int kq  = lin & 7;
            int grow = row0 + r;
            int kg   = k0 + kq * 4;
            float4 v = make_float4(0.f, 0.f, 0.f, 0.f);
            if (grow < M) {
                if (kg + 3 < K) {
                    v = *reinterpret_cast<const float4*>(A + (size_t)grow * K + kg);
                } else {
                    float t0 = (kg + 0 < K) ? A[(size_t)grow * K + kg + 0] : 0.f;
                    float t1 = (kg + 1 < K) ? A[(size_t)grow * K + kg + 1] : 0.f;
                    float t2 = (kg + 2 < K) ? A[(size_t)grow * K + kg + 2] : 0.f;
                    float t3 = (kg + 3 < K) ? A[(size_t)grow * K + kg + 3] : 0.f;
                    v = make_float4(t0, t1, t2, t3);
                }
            }
            As[kq * 4 + 0][r] = v.x;
            As[kq * 4 + 1][r] = v.y;
            As[kq * 4 + 2][r] = v.z;
            As[kq * 4 + 3][r] = v.w;
        }
        __syncthreads();
#pragma unroll
        for (int k = 0; k < BKK; k++) {
            float a[8];
#pragma unroll
            for (int i = 0; i < 8; i++) a[i] = As[k][ty * 8 + i];
            float4 bv = *reinterpret_cast<const float4*>(&Ws[k][tx * 4]);
#pragma unroll
            for (int i = 0; i < 8; i++) {
                acc[i][0] += a[i] * bv.x;
                acc[i][1] += a[i] * bv.y;
                acc[i][2] += a[i] * bv.z;
                acc[i][3] += a[i] * bv.w;
            }
        }
        __syncthreads();
    }

#pragma unroll
    for (int i = 0; i < 8; i++) {
        int grow = row0 + ty * 8 + i;
        if (grow >= M) continue;
        float dv = dinv[grow];
        float4 hv = make_float4(acc[i][0] * dv, acc[i][1] * dv,
                                acc[i][2] * dv, acc[i][3] * dv);
        *reinterpret_cast<float4*>(h + (size_t)grow * BN + tx * 4) = hv;
    }
}

// ---------------- gather: out[d] = relu( dd * (sum_{e:dst=d} h'[src] + h'[d]) + b ) ----
__global__ __launch_bounds__(256) void gather_agg(
    const float* __restrict__ h, const float* __restrict__ dinv,
    const int* __restrict__ off, const int* __restrict__ deg,
    const int* __restrict__ csr_src,
    const float* __restrict__ bias, float* __restrict__ out)
{
    int gid = blockIdx.x * 256 + threadIdx.x;
    int node = gid >> 5;
    if (node >= N_NODES) return;
    int lane = gid & 31;

    int beg = off[node];
    int end = beg + deg[node];
    float dd = dinv[node];

    float4 acc = *reinterpret_cast<const float4*>(h + (size_t)node * HID + lane * 4); // h'[d]
    float4 acc2 = make_float4(0.f, 0.f, 0.f, 0.f);

    int j = beg;
    for (; j + 1 < end; j += 2) {
        int s0 = csr_src[j];
        int s1 = csr_src[j + 1];
        float4 v0 = *reinterpret_cast<const float4*>(h + (size_t)s0 * HID + lane * 4);
        float4 v1 = *reinterpret_cast<const float4*>(h + (size_t)s1 * HID + lane * 4);
        acc.x += v0.x;  acc.y += v0.y;  acc.z += v0.z;  acc.w += v0.w;
        acc2.x += v1.x; acc2.y += v1.y; acc2.z += v1.z; acc2.w += v1.w;
    }
    if (j < end) {
        int s = csr_src[j];
        float4 v = *reinterpret_cast<const float4*>(h + (size_t)s * HID + lane * 4);
        acc.x += v.x; acc.y += v.y; acc.z += v.z; acc.w += v.w;
    }
    acc.x += acc2.x; acc.y += acc2.y; acc.z += acc2.z; acc.w += acc2.w;

    float4 bb = *reinterpret_cast<const float4*>(bias + lane * 4);
    float4 o = make_float4(fmaxf(acc.x * dd + bb.x, 0.f),
                           fmaxf(acc.y * dd + bb.y, 0.f),
                           fmaxf(acc.z * dd + bb.z, 0.f),
                           fmaxf(acc.w * dd + bb.w, 0.f));
    *reinterpret_cast<float4*>(out + (size_t)node * HID + lane * 4) = o;
}

// ---------------- fused mean-pool + head ----------------
__global__ __launch_bounds__(128) void pool_head(
    const float* __restrict__ xbuf, const int* __restrict__ starts,
    const float* __restrict__ Wp, const float* __restrict__ bp,
    float* __restrict__ out)
{
    __shared__ float p[128];
    int g = blockIdx.x;
    int t = threadIdx.x;
    int s0 = starts[g], s1 = starts[g + 1];
    float acc = 0.f;
    for (int n = s0; n < s1; ++n) acc += xbuf[(size_t)n * HID + t];
    float cntf = (float)(s1 - s0);
    p[t] = acc / fmaxf(cntf, 1.0f);
    __syncthreads();
    float o = bp[t];
#pragma unroll 8
    for (int k = 0; k < HID; k++) o += p[k] * Wp[(size_t)k * OUT_DIM + t];
    out[(size_t)g * OUT_DIM + t] = o;
}

extern "C" void kernel_launch(void* const* d_in, const int* in_sizes, int n_in,
                              void* d_out, int out_size, void* d_ws, size_t ws_size,
                              hipStream_t stream) {
    const float* x   = (const float*)d_in[0];
    const int*   ei  = (const int*)d_in[1];
    const int*   src = ei;
    const int*   dst = ei + N_EDGES;
    const int*   batch = (const int*)d_in[2];
    const float* W1 = (const float*)d_in[3];
    const float* b1 = (const float*)d_in[4];
    const float* W2 = (const float*)d_in[5];
    const float* b2 = (const float*)d_in[6];
    const float* Wp = (const float*)d_in[7];
    const float* bp = (const float*)d_in[8];
    float* out = (float*)d_out;

    // ---- workspace layout (4-byte units) ----
    float* ws     = (float*)d_ws;
    float* dinv   = ws;                         // 50,048
    int*   deg    = (int*)(ws + 50048);         // 50,048
    int*   total  = deg + 50048;                // 32 (1 used)
    int*   off    = total + 32;                 // 50,056
    int*   csr_src= off + 50056;                // 600,000
    int*   starts = csr_src + 600000;           // 1,024 (1001 used)
    float* hbuf   = (float*)(starts + 1024);    // 6,400,000
    float* xbuf   = hbuf + 6400000;             // 6,400,000
    // alias: cursor lives in xbuf until gather1 writes xbuf
    int*   cursor = (int*)xbuf;

    // ---- CSR build ----
    hipMemsetAsync(deg, 0, (50048 + 32) * sizeof(int), stream);   // deg + total
    deg_count<<<(N_EDGES + 255) / 256, 256, 0, stream>>>(dst, deg);
    dinv_from_deg<<<(N_NODES + 255) / 256, 256, 0, stream>>>(deg, dinv);
    alloc_off<<<(N_NODES + 255) / 256, 256, 0, stream>>>(deg, off, total);
    hipMemsetAsync(cursor, 0, N_NODES * sizeof(int), stream);
    fill_csr<<<(N_EDGES + 255) / 256, 256, 0, stream>>>(src, dst, off, cursor, csr_src);
    graph_bounds<<<(N_NODES + 255) / 256, 256, 0, stream>>>(batch, starts);

    const int gemm_blocks = (N_NODES + BM - 1) / BM;
    const int gather_blocks = (N_NODES * 32 + 255) / 256;

    // ---- layer 1 ----
    gemm_hs<<<gemm_blocks, 256, 0, stream>>>(x, W1, dinv, hbuf, N_NODES, IN_DIM);
    gather_agg<<<gather_blocks, 256, 0, stream>>>(hbuf, dinv, off, deg, csr_src, b1, xbuf);

    // ---- layer 2 ----
    gemm_hs<<<gemm_blocks, 256, 0, stream>>>(xbuf, W2, dinv, hbuf, N_NODES, HID);
    gather_agg<<<gather_blocks, 256, 0, stream>>>(hbuf, dinv, off, deg, csr_src, b2, xbuf);

    // ---- pool + head ----
    pool_head<<<N_GRAPHS, 128, 0, stream>>>(xbuf, starts, Wp, bp, out);
}

// Round 4
// 233.592 us; speedup vs baseline: 9.6720x; 1.1638x over previous
//
#include <hip/hip_runtime.h>
#include <hip/hip_bf16.h>

#define N_NODES 50000
#define N_EDGES 600000
#define N_GRAPHS 1000
#define IN_DIM 100
#define HID 128
#define OUT_DIM 128

#define BM 64
#define BN 128
#define BKK 32

__device__ inline unsigned short f2bf(float f) {
    __hip_bfloat16 b = __float2bfloat16(f);
    return *reinterpret_cast<unsigned short*>(&b);
}
__device__ inline float bflo(unsigned int u) { return __uint_as_float(u << 16); }
__device__ inline float bfhi(unsigned int u) { return __uint_as_float(u & 0xffff0000u); }

// ---------------- degree (int) ----------------
__global__ __launch_bounds__(256) void deg_count(const int* __restrict__ dst, int* __restrict__ deg) {
    int e = blockIdx.x * 256 + threadIdx.x;
    if (e < N_EDGES) atomicAdd(&deg[dst[e]], 1);
}

__global__ __launch_bounds__(256) void dinv_from_deg(const int* __restrict__ deg, float* __restrict__ dinv) {
    int i = blockIdx.x * 256 + threadIdx.x;
    if (i < N_NODES) dinv[i] = rsqrtf((float)deg[i] + 1.0f);
}

// ---------------- range allocator: off[i] = disjoint base for node i's edges ----
__global__ __launch_bounds__(256) void alloc_off(const int* __restrict__ deg,
                                                 int* __restrict__ off,
                                                 int* __restrict__ total) {
    int i = blockIdx.x * 256 + threadIdx.x;
    int v = (i < N_NODES) ? deg[i] : 0;
    int lane = threadIdx.x & 63;
    int wid  = threadIdx.x >> 6;
    int x = v;
#pragma unroll
    for (int d = 1; d < 64; d <<= 1) {
        int y = __shfl_up(x, d, 64);
        if (lane >= d) x += y;
    }
    __shared__ int wsum[4];
    __shared__ int wbase[4];
    if (lane == 63) wsum[wid] = x;
    __syncthreads();
    if (threadIdx.x == 0) {
        int s0 = wsum[0], s1 = wsum[1], s2 = wsum[2], s3 = wsum[3];
        int base = atomicAdd(total, s0 + s1 + s2 + s3);
        wbase[0] = base;
        wbase[1] = base + s0;
        wbase[2] = base + s0 + s1;
        wbase[3] = base + s0 + s1 + s2;
    }
    __syncthreads();
    if (i < N_NODES) off[i] = wbase[wid] + x - v;
}

// ---------------- fill CSR: csr_src grouped by dst ----------------
__global__ __launch_bounds__(256) void fill_csr(
    const int* __restrict__ src, const int* __restrict__ dst,
    const int* __restrict__ off, int* __restrict__ cursor, int* __restrict__ csr_src)
{
    int e = blockIdx.x * 256 + threadIdx.x;
    if (e >= N_EDGES) return;
    int d = dst[e];
    int pos = off[d] + atomicAdd(&cursor[d], 1);
    csr_src[pos] = src[e];
}

// ---------------- graph segment boundaries from sorted batch ----------------
__global__ __launch_bounds__(256) void graph_bounds(const int* __restrict__ batch, int* __restrict__ starts) {
    int i = blockIdx.x * 256 + threadIdx.x;
    if (i >= N_NODES) return;
    int b = batch[i];
    if (i == 0) {
        for (int g = 0; g <= b; ++g) starts[g] = 0;
    } else {
        int pb = batch[i - 1];
        for (int g = pb + 1; g <= b; ++g) starts[g] = i;
    }
    if (i == N_NODES - 1) {
        for (int g = b + 1; g <= N_GRAPHS; ++g) starts[g] = N_NODES;
    }
}

// ---------------- GEMM: h' = bf16( (A@W) * dinv[row] )  (f32 math, LDS-tiled) ----
__global__ __launch_bounds__(256) void gemm_hs(
    const float* __restrict__ A, const float* __restrict__ W,
    const float* __restrict__ dinv, unsigned int* __restrict__ hb, int M, int K)
{
    __shared__ float As[BKK][BM + 4];
    __shared__ float Ws[BKK][BN];
    const int tid = threadIdx.x;
    const int row0 = blockIdx.x * BM;
    const int tx = tid & 31;   // col group: cols tx*4..tx*4+3
    const int ty = tid >> 5;   // row group: rows ty*8..ty*8+7

    float acc[8][4];
#pragma unroll
    for (int i = 0; i < 8; i++)
#pragma unroll
        for (int j = 0; j < 4; j++) acc[i][j] = 0.0f;

    for (int k0 = 0; k0 < K; k0 += BKK) {
#pragma unroll
        for (int it = 0; it < 4; ++it) {
            int lin = tid + it * 256;
            int kl  = lin >> 5;
            int c4  = lin & 31;
            int kg  = k0 + kl;
            float4 v = make_float4(0.f, 0.f, 0.f, 0.f);
            if (kg < K) v = *reinterpret_cast<const float4*>(W + (size_t)kg * BN + c4 * 4);
            *reinterpret_cast<float4*>(&Ws[kl][c4 * 4]) = v;
        }
#pragma unroll
        for (int it = 0; it < 2; ++it) {
            int lin = tid + it * 256;
            int r   = lin >> 3;
            int kq  = lin & 7;
            int grow = row0 + r;
            int kg   = k0 + kq * 4;
            float4 v = make_float4(0.f, 0.f, 0.f, 0.f);
            if (grow < M) {
                if (kg + 3 < K) {
                    v = *reinterpret_cast<const float4*>(A + (size_t)grow * K + kg);
                } else {
                    float t0 = (kg + 0 < K) ? A[(size_t)grow * K + kg + 0] : 0.f;
                    float t1 = (kg + 1 < K) ? A[(size_t)grow * K + kg + 1] : 0.f;
                    float t2 = (kg + 2 < K) ? A[(size_t)grow * K + kg + 2] : 0.f;
                    float t3 = (kg + 3 < K) ? A[(size_t)grow * K + kg + 3] : 0.f;
                    v = make_float4(t0, t1, t2, t3);
                }
            }
            As[kq * 4 + 0][r] = v.x;
            As[kq * 4 + 1][r] = v.y;
            As[kq * 4 + 2][r] = v.z;
            As[kq * 4 + 3][r] = v.w;
        }
        __syncthreads();
#pragma unroll
        for (int k = 0; k < BKK; k++) {
            float a[8];
#pragma unroll
            for (int i = 0; i < 8; i++) a[i] = As[k][ty * 8 + i];
            float4 bv = *reinterpret_cast<const float4*>(&Ws[k][tx * 4]);
#pragma unroll
            for (int i = 0; i < 8; i++) {
                acc[i][0] += a[i] * bv.x;
                acc[i][1] += a[i] * bv.y;
                acc[i][2] += a[i] * bv.z;
                acc[i][3] += a[i] * bv.w;
            }
        }
        __syncthreads();
    }

#pragma unroll
    for (int i = 0; i < 8; i++) {
        int grow = row0 + ty * 8 + i;
        if (grow >= M) continue;
        float dv = dinv[grow];
        uint2 pk;
        pk.x = (unsigned int)f2bf(acc[i][0] * dv) | ((unsigned int)f2bf(acc[i][1] * dv) << 16);
        pk.y = (unsigned int)f2bf(acc[i][2] * dv) | ((unsigned int)f2bf(acc[i][3] * dv) << 16);
        // row stride = 32 uint2 (128 bf16); thread tx owns uint2 slot tx
        *reinterpret_cast<uint2*>(hb + (size_t)grow * 64 + tx * 2) = pk;
    }
}

// ---- gather: out[d] = relu( dd * (sum_{e:dst=d} h'[src] + h'[d]) + b ), h' in bf16 ----
__global__ __launch_bounds__(256) void gather_agg(
    const uint2* __restrict__ hp, const float* __restrict__ dinv,
    const int* __restrict__ off, const int* __restrict__ deg,
    const int* __restrict__ csr_src,
    const float* __restrict__ bias, float* __restrict__ out)
{
    int gid = blockIdx.x * 256 + threadIdx.x;
    int node = gid >> 5;
    if (node >= N_NODES) return;
    int lane = gid & 31;

    int beg = off[node];
    int end = beg + deg[node];
    float dd = dinv[node];

    uint2 self = hp[(size_t)node * 32 + lane];
    float4 a0 = make_float4(bflo(self.x), bfhi(self.x), bflo(self.y), bfhi(self.y));
    float4 a1 = make_float4(0.f, 0.f, 0.f, 0.f);
    float4 a2 = make_float4(0.f, 0.f, 0.f, 0.f);
    float4 a3 = make_float4(0.f, 0.f, 0.f, 0.f);

    int j = beg;
    for (; j + 3 < end; j += 4) {
        int s0 = csr_src[j + 0];
        int s1 = csr_src[j + 1];
        int s2 = csr_src[j + 2];
        int s3 = csr_src[j + 3];
        uint2 v0 = hp[(size_t)s0 * 32 + lane];
        uint2 v1 = hp[(size_t)s1 * 32 + lane];
        uint2 v2 = hp[(size_t)s2 * 32 + lane];
        uint2 v3 = hp[(size_t)s3 * 32 + lane];
        a0.x += bflo(v0.x); a0.y += bfhi(v0.x); a0.z += bflo(v0.y); a0.w += bfhi(v0.y);
        a1.x += bflo(v1.x); a1.y += bfhi(v1.x); a1.z += bflo(v1.y); a1.w += bfhi(v1.y);
        a2.x += bflo(v2.x); a2.y += bfhi(v2.x); a2.z += bflo(v2.y); a2.w += bfhi(v2.y);
        a3.x += bflo(v3.x); a3.y += bfhi(v3.x); a3.z += bflo(v3.y); a3.w += bfhi(v3.y);
    }
    for (; j < end; ++j) {
        int s = csr_src[j];
        uint2 v = hp[(size_t)s * 32 + lane];
        a0.x += bflo(v.x); a0.y += bfhi(v.x); a0.z += bflo(v.y); a0.w += bfhi(v.y);
    }
    a0.x += a1.x + a2.x + a3.x;
    a0.y += a1.y + a2.y + a3.y;
    a0.z += a1.z + a2.z + a3.z;
    a0.w += a1.w + a2.w + a3.w;

    float4 bb = *reinterpret_cast<const float4*>(bias + lane * 4);
    float4 o = make_float4(fmaxf(a0.x * dd + bb.x, 0.f),
                           fmaxf(a0.y * dd + bb.y, 0.f),
                           fmaxf(a0.z * dd + bb.z, 0.f),
                           fmaxf(a0.w * dd + bb.w, 0.f));
    *reinterpret_cast<float4*>(out + (size_t)node * HID + lane * 4) = o;
}

// ---------------- fused mean-pool + head ----------------
__global__ __launch_bounds__(128) void pool_head(
    const float* __restrict__ xbuf, const int* __restrict__ starts,
    const float* __restrict__ Wp, const float* __restrict__ bp,
    float* __restrict__ out)
{
    __shared__ float p[128];
    int g = blockIdx.x;
    int t = threadIdx.x;
    int s0 = starts[g], s1 = starts[g + 1];
    float acc = 0.f;
    for (int n = s0; n < s1; ++n) acc += xbuf[(size_t)n * HID + t];
    float cntf = (float)(s1 - s0);
    p[t] = acc / fmaxf(cntf, 1.0f);
    __syncthreads();
    float o = bp[t];
#pragma unroll 8
    for (int k = 0; k < HID; k++) o += p[k] * Wp[(size_t)k * OUT_DIM + t];
    out[(size_t)g * OUT_DIM + t] = o;
}

extern "C" void kernel_launch(void* const* d_in, const int* in_sizes, int n_in,
                              void* d_out, int out_size, void* d_ws, size_t ws_size,
                              hipStream_t stream) {
    const float* x   = (const float*)d_in[0];
    const int*   ei  = (const int*)d_in[1];
    const int*   src = ei;
    const int*   dst = ei + N_EDGES;
    const int*   batch = (const int*)d_in[2];
    const float* W1 = (const float*)d_in[3];
    const float* b1 = (const float*)d_in[4];
    const float* W2 = (const float*)d_in[5];
    const float* b2 = (const float*)d_in[6];
    const float* Wp = (const float*)d_in[7];
    const float* bp = (const float*)d_in[8];
    float* out = (float*)d_out;

    // ---- workspace layout (4-byte units) ----
    float* ws     = (float*)d_ws;
    float* dinv   = ws;                         // 50,048
    int*   deg    = (int*)(ws + 50048);         // 50,048
    int*   total  = deg + 50048;                // 32 (1 used)
    int*   off    = total + 32;                 // 50,056
    int*   csr_src= off + 50056;                // 600,000
    int*   starts = csr_src + 600000;           // 1,024 (1001 used)
    unsigned int* hb = (unsigned int*)(starts + 1024); // 3,200,000 u32 (50000 x 128 bf16)
    float* xbuf   = (float*)(hb + 3200000);     // 6,400,000 f
    // alias: cursor lives in xbuf until gather1 writes xbuf
    int*   cursor = (int*)xbuf;

    // ---- CSR build ----
    hipMemsetAsync(deg, 0, (50048 + 32) * sizeof(int), stream);   // deg + total
    deg_count<<<(N_EDGES + 255) / 256, 256, 0, stream>>>(dst, deg);
    dinv_from_deg<<<(N_NODES + 255) / 256, 256, 0, stream>>>(deg, dinv);
    alloc_off<<<(N_NODES + 255) / 256, 256, 0, stream>>>(deg, off, total);
    hipMemsetAsync(cursor, 0, N_NODES * sizeof(int), stream);
    fill_csr<<<(N_EDGES + 255) / 256, 256, 0, stream>>>(src, dst, off, cursor, csr_src);
    graph_bounds<<<(N_NODES + 255) / 256, 256, 0, stream>>>(batch, starts);

    const int gemm_blocks = (N_NODES + BM - 1) / BM;
    const int gather_blocks = (N_NODES * 32 + 255) / 256;

    // ---- layer 1 ----
    gemm_hs<<<gemm_blocks, 256, 0, stream>>>(x, W1, dinv, hb, N_NODES, IN_DIM);
    gather_agg<<<gather_blocks, 256, 0, stream>>>((const uint2*)hb, dinv, off, deg, csr_src, b1, xbuf);

    // ---- layer 2 ----
    gemm_hs<<<gemm_blocks, 256, 0, stream>>>(xbuf, W2, dinv, hb, N_NODES, HID);
    gather_agg<<<gather_blocks, 256, 0, stream>>>((const uint2*)hb, dinv, off, deg, csr_src, b2, xbuf);

    // ---- pool + head ----
    pool_head<<<N_GRAPHS, 128, 0, stream>>>(xbuf, starts, Wp, bp, out);
}